// Round 2
// baseline (5995.637 us; speedup 1.0000x reference)
//
#include <hip/hip_runtime.h>
#include <hip/hip_bf16.h>

// HeunIntegrator fused persistent kernel, bf16x2-split MFMA (f32-class precision).
// B=8192 x D=1024, R=256, 16 Heun steps. 256 blocks x 512 thr (8 waves), 32 rows/block.
// Per eval: GEMM1 p=v*W^T (k=1024), square, GEMM2 g=p^2*U^T (k=256), both as
// (Ahi+Alo)(Bhi+Blo) with 3 MFMAs (drop lo*lo): rel err ~2^-18 -> no wrap flips.
// Elementwise path mirrors np float32 bitwise-intent: __f*_rn (no contraction),
// fmodf-based wrap identical to np.mod. W/U pre-split hi/lo into fragment-packed
// layout in d_ws (coalesced 1KB/wave B-loads). LDS 160KB: Vhi/Vlo 64K+64K,
// Phi/Plo 16K+16K, XOR-swizzled (byte ^= (row&7)<<4) for conflict-free ds_read_b128.

typedef __attribute__((ext_vector_type(8))) short bf16x8;
typedef __attribute__((ext_vector_type(4))) float f32x4;

#define LDS_BYTES 163840
#define VHI 0
#define VLO 65536
#define PHI 131072
#define PLO 147456

#define PI_F    3.14159265358979323846f
#define TWOPI_F 6.28318530717958647692f

static __device__ __forceinline__ short f2b(float f) {
    return __builtin_bit_cast(short, __float2bfloat16(f));
}
static __device__ __forceinline__ float b2f(short s) {
    unsigned u = ((unsigned)(unsigned short)s) << 16;
    return __builtin_bit_cast(float, u);
}

// Pack W [256][1024] and U [1024][256] into fragment-ordered bf16 hi/lo planes:
// W: o = ((rt*32+kt)*64 + lane)*8 + j  <->  W[rt*16+l16][kt*32+lg*8+j]
// U: o = ((dt*8 +kt)*64 + lane)*8 + j  <->  U[dt*16+l16][kt*32+lg*8+j]
__global__ void cvt_wu(const float* __restrict__ U, const float* __restrict__ W,
                       short* __restrict__ Whi, short* __restrict__ Wlo,
                       short* __restrict__ Uhi, short* __restrict__ Ulo) {
    int o = blockIdx.x * 256 + threadIdx.x;          // 0..262143
    int j = o & 7, lane = (o >> 3) & 63;
    int l16 = lane & 15, lg = lane >> 4;
    {
        int kt = (o >> 9) & 31, rt = o >> 14;
        float wv = W[(rt * 16 + l16) * 1024 + kt * 32 + lg * 8 + j];
        short h = f2b(wv);
        Whi[o] = h;
        Wlo[o] = f2b(__fsub_rn(wv, b2f(h)));
    }
    {
        int kt = (o >> 9) & 7, dt = o >> 12;
        float uv = U[(dt * 16 + l16) * 256 + kt * 32 + lg * 8 + j];
        short h = f2b(uv);
        Uhi[o] = h;
        Ulo[o] = f2b(__fsub_rn(uv, b2f(h)));
    }
}

static __device__ __forceinline__ f32x4 triple(bf16x8 ah, bf16x8 al,
                                               bf16x8 bh, bf16x8 bl, f32x4 acc) {
    acc = __builtin_amdgcn_mfma_f32_16x16x32_bf16(al, bh, acc, 0, 0, 0);
    acc = __builtin_amdgcn_mfma_f32_16x16x32_bf16(ah, bl, acc, 0, 0, 0);
    acc = __builtin_amdgcn_mfma_f32_16x16x32_bf16(ah, bh, acc, 0, 0, 0);
    return acc;
}

// np.mod(a, 2pi) - pi with a = s + pi; fmod is exact, single adjust-add like numpy.
static __device__ __forceinline__ float wrapf(float s) {
    float a = __fadd_rn(s, PI_F);
    float m = fmodf(a, TWOPI_F);
    if (m < 0.0f) m = __fadd_rn(m, TWOPI_F);
    return __fsub_rn(m, PI_F);
}

__global__ __launch_bounds__(512, 2) void heun_fused(
    const float* __restrict__ x_in, const float* __restrict__ v_in,
    const float* __restrict__ fo_in,
    const short* __restrict__ Whi, const short* __restrict__ Wlo,
    const short* __restrict__ Uhi, const short* __restrict__ Ulo,
    float* __restrict__ out)
{
    extern __shared__ char smem[];
    const int tid = threadIdx.x;
    const int w = tid >> 6, l = tid & 63, l16 = l & 15, lg = l >> 4;
    const int row0 = blockIdx.x << 5;

    // State in C/D fragment layout: (mt,nt,rr) <-> row=mt*16+lg*4+rr, col=w*128+nt*16+l16
    float xr[2][8][4], vr[2][8][4], fk[2][8][4];

#pragma unroll
    for (int mt = 0; mt < 2; ++mt)
#pragma unroll
      for (int nt = 0; nt < 8; ++nt) {
        const size_t base = (size_t)(row0 + mt*16 + lg*4) * 1024 + (w*128 + nt*16 + l16);
#pragma unroll
        for (int rr = 0; rr < 4; ++rr) {
            xr[mt][nt][rr] = x_in[base + (size_t)rr * 1024];
            vr[mt][nt][rr] = v_in[base + (size_t)rr * 1024];
            fk[mt][nt][rr] = fo_in[base + (size_t)rr * 1024];
        }
      }

    const int asw = (l16 & 7) << 4;
    const char* const vh0 = smem + VHI + (l16 << 11);
    const char* const vh1 = smem + VHI + ((16 + l16) << 11);
    const char* const vl0 = smem + VLO + (l16 << 11);
    const char* const vl1 = smem + VLO + ((16 + l16) << 11);
    const char* const ph0 = smem + PHI + (l16 << 9);
    const char* const ph1 = smem + PHI + ((16 + l16) << 9);
    const char* const pl0 = smem + PLO + (l16 << 9);
    const char* const pl1 = smem + PLO + ((16 + l16) << 9);

    const char* const whc = (const char*)Whi;
    const char* const wlc = (const char*)Wlo;
    const char* const uhc = (const char*)Uhi;
    const char* const ulc = (const char*)Ulo;

    int wb[2], ub[8];
#pragma unroll
    for (int ntp = 0; ntp < 2; ++ntp) wb[ntp] = ((w*2 + ntp) << 15) + (l << 4);
#pragma unroll
    for (int nt = 0; nt < 8; ++nt)    ub[nt]  = ((w*8 + nt) << 13) + (l << 4);

    // stage split(v) into Vb planes (element row/col as above)
#pragma unroll
    for (int mt = 0; mt < 2; ++mt)
#pragma unroll
      for (int nt = 0; nt < 8; ++nt) {
        const int colb0 = (w*128 + nt*16 + l16) << 1;
#pragma unroll
        for (int rr = 0; rr < 4; ++rr) {
            const int row = mt*16 + lg*4 + rr;
            const int cb = colb0 ^ ((row & 7) << 4);
            float val = vr[mt][nt][rr];
            short h = f2b(val);
            *(short*)(smem + VHI + (row << 11) + cb) = h;
            *(short*)(smem + VLO + (row << 11) + cb) = f2b(__fsub_rn(val, b2f(h)));
        }
      }
    __syncthreads();

#pragma unroll 1
    for (int s = 0; s < 16; ++s) {
#pragma unroll 1
        for (int cc = 0; cc < 2; ++cc) {
            // ---- GEMM1: p[32,256] = V * W^T, wave cols w*32..+31 ----
            f32x4 p[2][2];
#pragma unroll
            for (int mt = 0; mt < 2; ++mt)
#pragma unroll
              for (int ntp = 0; ntp < 2; ++ntp) p[mt][ntp] = (f32x4){0.f,0.f,0.f,0.f};

#pragma unroll 4
            for (int kt = 0; kt < 32; ++kt) {
                const int ao = ((kt << 6) + (lg << 4)) ^ asw;
                bf16x8 ah0 = *(const bf16x8*)(vh0 + ao);
                bf16x8 al0 = *(const bf16x8*)(vl0 + ao);
                bf16x8 ah1 = *(const bf16x8*)(vh1 + ao);
                bf16x8 al1 = *(const bf16x8*)(vl1 + ao);
#pragma unroll
                for (int ntp = 0; ntp < 2; ++ntp) {
                    bf16x8 bh = *(const bf16x8*)(whc + wb[ntp] + (kt << 10));
                    bf16x8 bl = *(const bf16x8*)(wlc + wb[ntp] + (kt << 10));
                    p[0][ntp] = triple(ah0, al0, bh, bl, p[0][ntp]);
                    p[1][ntp] = triple(ah1, al1, bh, bl, p[1][ntp]);
                }
            }
            // ---- square -> Pb hi/lo ----
#pragma unroll
            for (int mt = 0; mt < 2; ++mt)
#pragma unroll
              for (int ntp = 0; ntp < 2; ++ntp) {
                const int colb0 = (w*32 + ntp*16 + l16) << 1;
#pragma unroll
                for (int rr = 0; rr < 4; ++rr) {
                    const int row = mt*16 + lg*4 + rr;
                    const int cb = colb0 ^ ((row & 7) << 4);
                    float ps = __fmul_rn(p[mt][ntp][rr], p[mt][ntp][rr]);
                    short h = f2b(ps);
                    *(short*)(smem + PHI + (row << 9) + cb) = h;
                    *(short*)(smem + PLO + (row << 9) + cb) = f2b(__fsub_rn(ps, b2f(h)));
                }
              }
            __syncthreads();   // Pb complete; all Vb reads done

            // ---- GEMM2: g[32,1024] = Pb * U^T, wave cols w*128..+127, 4 quarters ----
#pragma unroll
            for (int q = 0; q < 4; ++q) {
                f32x4 g[2][2];
#pragma unroll
                for (int mt = 0; mt < 2; ++mt)
#pragma unroll
                  for (int n = 0; n < 2; ++n) g[mt][n] = (f32x4){0.f,0.f,0.f,0.f};

#pragma unroll
                for (int kt = 0; kt < 8; ++kt) {
                    const int ao = ((kt << 6) + (lg << 4)) ^ asw;
                    bf16x8 ah0 = *(const bf16x8*)(ph0 + ao);
                    bf16x8 al0 = *(const bf16x8*)(pl0 + ao);
                    bf16x8 ah1 = *(const bf16x8*)(ph1 + ao);
                    bf16x8 al1 = *(const bf16x8*)(pl1 + ao);
#pragma unroll
                    for (int n = 0; n < 2; ++n) {
                        const int nt = q*2 + n;
                        bf16x8 bh = *(const bf16x8*)(uhc + ub[nt] + (kt << 10));
                        bf16x8 bl = *(const bf16x8*)(ulc + ub[nt] + (kt << 10));
                        g[0][n] = triple(ah0, al0, bh, bl, g[0][n]);
                        g[1][n] = triple(ah1, al1, bh, bl, g[1][n]);
                    }
                }
                // ---- epilogue (np-exact elementwise) ----
#pragma unroll
                for (int mt = 0; mt < 2; ++mt)
#pragma unroll
                  for (int n = 0; n < 2; ++n) {
                    const int nt = q*2 + n;
                    const int colb0 = (w*128 + nt*16 + l16) << 1;
#pragma unroll
                    for (int rr = 0; rr < 4; ++rr) {
                        const int row = mt*16 + lg*4 + rr;
                        const int cb = colb0 ^ ((row & 7) << 4);
                        const float dv = __fsub_rn(fk[mt][nt][rr], g[mt][n][rr]);
                        float stagev;
                        if (cc == 0) {
                            const float cv = vr[mt][nt][rr];
                            // v_pred = cv + dt*dv1 (mul then add, like ref)
                            const float vp = __fadd_rn(cv, __fmul_rn(0.01f, dv));
                            // nx = wrap(cx + 0.005*(cv + v_pred)) — full x-step here
                            const float t  = __fadd_rn(cv, vp);
                            const float sx = __fadd_rn(xr[mt][nt][rr], __fmul_rn(0.005f, t));
                            xr[mt][nt][rr] = wrapf(sx);
                            // v half-update: cv + 0.005*dv1 (completed at cc=1)
                            vr[mt][nt][rr] = __fadd_rn(cv, __fmul_rn(0.005f, dv));
                            stagev = vp;
                        } else {
                            const float nv = __fadd_rn(vr[mt][nt][rr], __fmul_rn(0.005f, dv));
                            vr[mt][nt][rr] = nv;
                            stagev = nv;
                        }
                        short h = f2b(stagev);
                        *(short*)(smem + VHI + (row << 11) + cb) = h;
                        *(short*)(smem + VLO + (row << 11) + cb) = f2b(__fsub_rn(stagev, b2f(h)));
                    }
                  }
            }
            __syncthreads();   // Vb(next eval input) complete
        }
    }

    // ---- store outputs: [x | v] f32 ----
#pragma unroll
    for (int mt = 0; mt < 2; ++mt)
#pragma unroll
      for (int nt = 0; nt < 8; ++nt) {
        const size_t base = (size_t)(row0 + mt*16 + lg*4) * 1024 + (w*128 + nt*16 + l16);
#pragma unroll
        for (int rr = 0; rr < 4; ++rr) {
            out[base + (size_t)rr * 1024]           = xr[mt][nt][rr];
            out[8388608 + base + (size_t)rr * 1024] = vr[mt][nt][rr];
        }
      }
}

extern "C" void kernel_launch(void* const* d_in, const int* in_sizes, int n_in,
                              void* d_out, int out_size, void* d_ws, size_t ws_size,
                              hipStream_t stream) {
    const float* x = (const float*)d_in[0];
    const float* v = (const float*)d_in[1];
    const float* f = (const float*)d_in[2];
    const float* U = (const float*)d_in[3];
    const float* W = (const float*)d_in[4];
    short* Whi = (short*)d_ws;           // 4 x 262144 bf16 = 2 MB
    short* Wlo = Whi + 262144;
    short* Uhi = Wlo + 262144;
    short* Ulo = Uhi + 262144;

    hipFuncSetAttribute((const void*)heun_fused,
                        hipFuncAttributeMaxDynamicSharedMemorySize, LDS_BYTES);

    cvt_wu<<<1024, 256, 0, stream>>>(U, W, Whi, Wlo, Uhi, Ulo);
    heun_fused<<<256, 512, LDS_BYTES, stream>>>(x, v, f, Whi, Wlo, Uhi, Ulo, (float*)d_out);
}

// Round 3
// 4816.871 us; speedup vs baseline: 1.2447x; 1.2447x over previous
//
#include <hip/hip_runtime.h>
#include <hip/hip_bf16.h>

// HeunIntegrator fused persistent kernel, R3: spill-free + software-pipelined B-loads.
// Arithmetic is bit-identical to R2 (passed, absmax 0.0156): same bf16x2-split MFMA
// (triple: al*bh, ah*bl, ah*bh), same __f*_rn epilogue, same fmodf wrap, same k-order.
// Changes vs R2 (scheduling/memory only):
//  - force no longer register-resident: re-read from global per eval (prefetched).
//  - x state lives in d_out x-half (seeded by d2d copy), RMW once per step.
//  - persistent reg state = vr only (64 f32/lane); waves_per_eu(2,2) -> 256-reg budget.
//  - explicit prefetch queues for W/U loads (static slot indices via ko/ki nesting).

typedef __attribute__((ext_vector_type(8))) short bf16x8;
typedef __attribute__((ext_vector_type(4))) float f32x4;

#define LDS_BYTES 163840
#define VHI 0
#define VLO 65536
#define PHI 131072
#define PLO 147456

#define PI_F    3.14159265358979323846f
#define TWOPI_F 6.28318530717958647692f

static __device__ __forceinline__ short f2b(float f) {
    return __builtin_bit_cast(short, __float2bfloat16(f));
}
static __device__ __forceinline__ float b2f(short s) {
    unsigned u = ((unsigned)(unsigned short)s) << 16;
    return __builtin_bit_cast(float, u);
}

// Pack W [256][1024] and U [1024][256] into fragment-ordered bf16 hi/lo planes:
// W: o = ((rt*32+kt)*64 + lane)*8 + j  <->  W[rt*16+l16][kt*32+lg*8+j]
// U: o = ((dt*8 +kt)*64 + lane)*8 + j  <->  U[dt*16+l16][kt*32+lg*8+j]
__global__ void cvt_wu(const float* __restrict__ U, const float* __restrict__ W,
                       short* __restrict__ Whi, short* __restrict__ Wlo,
                       short* __restrict__ Uhi, short* __restrict__ Ulo) {
    int o = blockIdx.x * 256 + threadIdx.x;          // 0..262143
    int j = o & 7, lane = (o >> 3) & 63;
    int l16 = lane & 15, lg = lane >> 4;
    {
        int kt = (o >> 9) & 31, rt = o >> 14;
        float wv = W[(rt * 16 + l16) * 1024 + kt * 32 + lg * 8 + j];
        short h = f2b(wv);
        Whi[o] = h;
        Wlo[o] = f2b(__fsub_rn(wv, b2f(h)));
    }
    {
        int kt = (o >> 9) & 7, dt = o >> 12;
        float uv = U[(dt * 16 + l16) * 256 + kt * 32 + lg * 8 + j];
        short h = f2b(uv);
        Uhi[o] = h;
        Ulo[o] = f2b(__fsub_rn(uv, b2f(h)));
    }
}

static __device__ __forceinline__ f32x4 triple(bf16x8 ah, bf16x8 al,
                                               bf16x8 bh, bf16x8 bl, f32x4 acc) {
    acc = __builtin_amdgcn_mfma_f32_16x16x32_bf16(al, bh, acc, 0, 0, 0);
    acc = __builtin_amdgcn_mfma_f32_16x16x32_bf16(ah, bl, acc, 0, 0, 0);
    acc = __builtin_amdgcn_mfma_f32_16x16x32_bf16(ah, bh, acc, 0, 0, 0);
    return acc;
}

// np.mod(a, 2pi) - pi with a = s + pi; identical op sequence to the R2 pass.
static __device__ __forceinline__ float wrapf(float s) {
    float a = __fadd_rn(s, PI_F);
    float m = fmodf(a, TWOPI_F);
    if (m < 0.0f) m = __fadd_rn(m, TWOPI_F);
    return __fsub_rn(m, PI_F);
}

__global__ __attribute__((amdgpu_flat_work_group_size(512, 512),
                          amdgpu_waves_per_eu(2, 2)))
void heun_fused(
    const float* __restrict__ v_in, const float* __restrict__ fo_in,
    const short* __restrict__ Whi, const short* __restrict__ Wlo,
    const short* __restrict__ Uhi, const short* __restrict__ Ulo,
    float* __restrict__ xst,      // d_out x-half, pre-seeded with x_in; RMW'd per step
    float* __restrict__ vout)     // d_out v-half
{
    extern __shared__ char smem[];
    const int tid = threadIdx.x;
    const int w = tid >> 6, l = tid & 63, l16 = l & 15, lg = l >> 4;
    const int row0 = blockIdx.x << 5;

    // Persistent per-lane state: v only. (mt,nt,rr) <-> row=mt*16+lg*4+rr, col=w*128+nt*16+l16
    float vr[2][8][4];

    const int asw = (l16 & 7) << 4;
    const char* const vh0 = smem + VHI + (l16 << 11);
    const char* const vh1 = smem + VHI + ((16 + l16) << 11);
    const char* const vl0 = smem + VLO + (l16 << 11);
    const char* const vl1 = smem + VLO + ((16 + l16) << 11);
    const char* const ph0p = smem + PHI + (l16 << 9);
    const char* const ph1p = smem + PHI + ((16 + l16) << 9);
    const char* const pl0p = smem + PLO + (l16 << 9);
    const char* const pl1p = smem + PLO + ((16 + l16) << 9);

    const char* const whc = (const char*)Whi;
    const char* const wlc = (const char*)Wlo;
    const char* const uhc = (const char*)Uhi;
    const char* const ulc = (const char*)Ulo;

    int wb[2];
#pragma unroll
    for (int t = 0; t < 2; ++t) wb[t] = ((w*2 + t) << 15) + (l << 4);

    // ---- initial: load v, stage split(v) into Vb ----
#pragma unroll
    for (int mt = 0; mt < 2; ++mt)
#pragma unroll
      for (int nt = 0; nt < 8; ++nt) {
        const size_t base = (size_t)(row0 + mt*16 + lg*4) * 1024 + (w*128 + nt*16 + l16);
        const int colb0 = (w*128 + nt*16 + l16) << 1;
#pragma unroll
        for (int rr = 0; rr < 4; ++rr) {
            float val = v_in[base + (size_t)rr * 1024];
            vr[mt][nt][rr] = val;
            const int row = mt*16 + lg*4 + rr;
            const int cb = colb0 ^ ((row & 7) << 4);
            short h = f2b(val);
            *(short*)(smem + VHI + (row << 11) + cb) = h;
            *(short*)(smem + VLO + (row << 11) + cb) = f2b(__fsub_rn(val, b2f(h)));
        }
      }
    __syncthreads();

#pragma unroll 1
    for (int s = 0; s < 16; ++s) {
#pragma unroll 1
        for (int cc = 0; cc < 2; ++cc) {
            // ================= GEMM1: p[32,256] = V * W^T, wave cols w*32..+31 =====
            f32x4 p[2][2];
#pragma unroll
            for (int mt = 0; mt < 2; ++mt)
#pragma unroll
              for (int t = 0; t < 2; ++t) p[mt][t] = (f32x4){0.f, 0.f, 0.f, 0.f};

            bf16x8 qh[4][2], ql[4][2];                 // depth-4 prefetch queue
#pragma unroll
            for (int i = 0; i < 4; ++i)
#pragma unroll
              for (int t = 0; t < 2; ++t) {
                qh[i][t] = *(const bf16x8*)(whc + wb[t] + (i << 10));
                ql[i][t] = *(const bf16x8*)(wlc + wb[t] + (i << 10));
              }

#pragma unroll 1
            for (int ko = 0; ko < 8; ++ko) {
#pragma unroll
                for (int ki = 0; ki < 4; ++ki) {       // slot = ki (static)
                    const int kt = ko*4 + ki;
                    const int ao = ((kt << 6) + (lg << 4)) ^ asw;
                    bf16x8 ah0 = *(const bf16x8*)(vh0 + ao);
                    bf16x8 al0 = *(const bf16x8*)(vl0 + ao);
                    bf16x8 ah1 = *(const bf16x8*)(vh1 + ao);
                    bf16x8 al1 = *(const bf16x8*)(vl1 + ao);
#pragma unroll
                    for (int t = 0; t < 2; ++t) {
                        p[0][t] = triple(ah0, al0, qh[ki][t], ql[ki][t], p[0][t]);
                        p[1][t] = triple(ah1, al1, qh[ki][t], ql[ki][t], p[1][t]);
                    }
                    if (ko < 7) {
#pragma unroll
                        for (int t = 0; t < 2; ++t) {
                            qh[ki][t] = *(const bf16x8*)(whc + wb[t] + ((kt + 4) << 10));
                            ql[ki][t] = *(const bf16x8*)(wlc + wb[t] + ((kt + 4) << 10));
                        }
                    }
                }
            }
            // ---- square -> Pb hi/lo ----
#pragma unroll
            for (int mt = 0; mt < 2; ++mt)
#pragma unroll
              for (int t = 0; t < 2; ++t) {
                const int colb0 = (w*32 + t*16 + l16) << 1;
#pragma unroll
                for (int rr = 0; rr < 4; ++rr) {
                    const int row = mt*16 + lg*4 + rr;
                    const int cb = colb0 ^ ((row & 7) << 4);
                    float ps = __fmul_rn(p[mt][t][rr], p[mt][t][rr]);
                    short h = f2b(ps);
                    *(short*)(smem + PHI + (row << 9) + cb) = h;
                    *(short*)(smem + PLO + (row << 9) + cb) = f2b(__fsub_rn(ps, b2f(h)));
                }
              }
            __syncthreads();   // Pb complete; all Vb reads done

            // ================= GEMM2: g[32,1024] = Pb * U^T, 4 quarters ===========
#pragma unroll
            for (int q = 0; q < 4; ++q) {
                // prefetch force (and x on cc==0) for this quarter
                float fpre[2][2][4], xpre[2][2][4];
#pragma unroll
                for (int mt = 0; mt < 2; ++mt)
#pragma unroll
                  for (int n = 0; n < 2; ++n) {
                    const size_t gb = (size_t)(row0 + mt*16 + lg*4) * 1024
                                    + (w*128 + (q*2 + n)*16 + l16);
#pragma unroll
                    for (int rr = 0; rr < 4; ++rr)
                        fpre[mt][n][rr] = fo_in[gb + (size_t)rr * 1024];
                    if (cc == 0) {
#pragma unroll
                        for (int rr = 0; rr < 4; ++rr)
                            xpre[mt][n][rr] = xst[gb + (size_t)rr * 1024];
                    }
                  }

                bf16x8 uqh[2][2], uql[2][2];           // depth-2 prefetch queue
#pragma unroll
                for (int i = 0; i < 2; ++i)
#pragma unroll
                  for (int n = 0; n < 2; ++n) {
                    const int ub = ((w*8 + q*2 + n) << 13) + (l << 4);
                    uqh[i][n] = *(const bf16x8*)(uhc + ub + (i << 10));
                    uql[i][n] = *(const bf16x8*)(ulc + ub + (i << 10));
                  }

                f32x4 g[2][2];
#pragma unroll
                for (int mt = 0; mt < 2; ++mt)
#pragma unroll
                  for (int n = 0; n < 2; ++n) g[mt][n] = (f32x4){0.f, 0.f, 0.f, 0.f};

#pragma unroll 1
                for (int ko = 0; ko < 4; ++ko) {
#pragma unroll
                    for (int ki = 0; ki < 2; ++ki) {   // slot = ki (static)
                        const int kt = ko*2 + ki;
                        const int ao = ((kt << 6) + (lg << 4)) ^ asw;
                        bf16x8 a0h = *(const bf16x8*)(ph0p + ao);
                        bf16x8 a0l = *(const bf16x8*)(pl0p + ao);
                        bf16x8 a1h = *(const bf16x8*)(ph1p + ao);
                        bf16x8 a1l = *(const bf16x8*)(pl1p + ao);
#pragma unroll
                        for (int n = 0; n < 2; ++n) {
                            g[0][n] = triple(a0h, a0l, uqh[ki][n], uql[ki][n], g[0][n]);
                            g[1][n] = triple(a1h, a1l, uqh[ki][n], uql[ki][n], g[1][n]);
                        }
                        if (ko < 3) {
#pragma unroll
                            for (int n = 0; n < 2; ++n) {
                                const int ub = ((w*8 + q*2 + n) << 13) + (l << 4);
                                uqh[ki][n] = *(const bf16x8*)(uhc + ub + ((kt + 2) << 10));
                                uql[ki][n] = *(const bf16x8*)(ulc + ub + ((kt + 2) << 10));
                            }
                        }
                    }
                }
                // ---- epilogue (identical op order to R2) ----
#pragma unroll
                for (int mt = 0; mt < 2; ++mt)
#pragma unroll
                  for (int n = 0; n < 2; ++n) {
                    const int nt = q*2 + n;
                    const size_t gb = (size_t)(row0 + mt*16 + lg*4) * 1024
                                    + (w*128 + nt*16 + l16);
                    const int colb0 = (w*128 + nt*16 + l16) << 1;
#pragma unroll
                    for (int rr = 0; rr < 4; ++rr) {
                        const int row = mt*16 + lg*4 + rr;
                        const int cb = colb0 ^ ((row & 7) << 4);
                        const float dv = __fsub_rn(fpre[mt][n][rr], g[mt][n][rr]);
                        float stagev;
                        if (cc == 0) {
                            const float cv = vr[mt][nt][rr];
                            const float vp = __fadd_rn(cv, __fmul_rn(0.01f, dv));
                            const float t  = __fadd_rn(cv, vp);
                            const float sx = __fadd_rn(xpre[mt][n][rr], __fmul_rn(0.005f, t));
                            xst[gb + (size_t)rr * 1024] = wrapf(sx);
                            vr[mt][nt][rr] = __fadd_rn(cv, __fmul_rn(0.005f, dv));
                            stagev = vp;
                        } else {
                            const float nv = __fadd_rn(vr[mt][nt][rr], __fmul_rn(0.005f, dv));
                            vr[mt][nt][rr] = nv;
                            stagev = nv;
                        }
                        short h = f2b(stagev);
                        *(short*)(smem + VHI + (row << 11) + cb) = h;
                        *(short*)(smem + VLO + (row << 11) + cb) = f2b(__fsub_rn(stagev, b2f(h)));
                    }
                  }
            }
            __syncthreads();   // Vb(next eval input) complete
        }
    }

    // ---- store v output (x already in place in xst) ----
#pragma unroll
    for (int mt = 0; mt < 2; ++mt)
#pragma unroll
      for (int nt = 0; nt < 8; ++nt) {
        const size_t base = (size_t)(row0 + mt*16 + lg*4) * 1024 + (w*128 + nt*16 + l16);
#pragma unroll
        for (int rr = 0; rr < 4; ++rr)
            vout[base + (size_t)rr * 1024] = vr[mt][nt][rr];
      }
}

extern "C" void kernel_launch(void* const* d_in, const int* in_sizes, int n_in,
                              void* d_out, int out_size, void* d_ws, size_t ws_size,
                              hipStream_t stream) {
    const float* x = (const float*)d_in[0];
    const float* v = (const float*)d_in[1];
    const float* f = (const float*)d_in[2];
    const float* U = (const float*)d_in[3];
    const float* W = (const float*)d_in[4];
    short* Whi = (short*)d_ws;           // 4 x 262144 bf16 = 2 MB
    short* Wlo = Whi + 262144;
    short* Uhi = Wlo + 262144;
    short* Ulo = Uhi + 262144;

    float* xst  = (float*)d_out;             // x state lives in the output buffer
    float* vout = (float*)d_out + 8388608;

    hipFuncSetAttribute((const void*)heun_fused,
                        hipFuncAttributeMaxDynamicSharedMemorySize, LDS_BYTES);

    // seed x state with x_in (device-to-device, stream-ordered; graph-capture safe)
    hipMemcpyAsync(xst, x, 8388608 * sizeof(float), hipMemcpyDeviceToDevice, stream);
    cvt_wu<<<1024, 256, 0, stream>>>(U, W, Whi, Wlo, Uhi, Ulo);
    heun_fused<<<256, 512, LDS_BYTES, stream>>>(v, f, Whi, Wlo, Uhi, Ulo, xst, vout);
}

// Round 6
// 2943.601 us; speedup vs baseline: 2.0368x; 1.6364x over previous
//
#include <hip/hip_runtime.h>
#include <hip/hip_bf16.h>

// HeunIntegrator fused persistent kernel, R5 (resubmit; R5 bench was lost to a GPU
// acquisition timeout): R4 with the fragment-order stride fixed.
// R4 crashed on an OOB read: heun_fused used c2-stride 1024 floats while perm_xf wrote
// c2-stride 256 (layout idx = b*32768 + w*4096 + c2*256 + l*4 + rr). All fragment-order
// accesses now use (c2 << 8). Arithmetic bit-identical to R2/R3 passes (absmax 0.0156).
//  - force and x pre-permuted into C-fragment order -> hot-loop global accesses are
//    lane-contiguous dwordx4 (full 128B lines, 1KB per wave per load).
//  - x state (permuted) lives in d_out x-half; force-perm in d_out v-half.
//  - tail: barrier -> read own xperm slots -> barrier -> scatter x/v original layout.

typedef __attribute__((ext_vector_type(8))) short bf16x8;
typedef __attribute__((ext_vector_type(4))) float f32x4;

#define LDS_BYTES 163840
#define VHI 0
#define VLO 65536
#define PHI 131072
#define PLO 147456

#define PI_F    3.14159265358979323846f
#define TWOPI_F 6.28318530717958647692f

static __device__ __forceinline__ short f2b(float f) {
    return __builtin_bit_cast(short, __float2bfloat16(f));
}
static __device__ __forceinline__ float b2f(short s) {
    unsigned u = ((unsigned)(unsigned short)s) << 16;
    return __builtin_bit_cast(float, u);
}

// Pack W [256][1024] and U [1024][256] into fragment-ordered bf16 hi/lo planes.
__global__ void cvt_wu(const float* __restrict__ U, const float* __restrict__ W,
                       short* __restrict__ Whi, short* __restrict__ Wlo,
                       short* __restrict__ Uhi, short* __restrict__ Ulo) {
    int o = blockIdx.x * 256 + threadIdx.x;          // 0..262143
    int j = o & 7, lane = (o >> 3) & 63;
    int l16 = lane & 15, lg = lane >> 4;
    {
        int kt = (o >> 9) & 31, rt = o >> 14;
        float wv = W[(rt * 16 + l16) * 1024 + kt * 32 + lg * 8 + j];
        short h = f2b(wv);
        Whi[o] = h;
        Wlo[o] = f2b(__fsub_rn(wv, b2f(h)));
    }
    {
        int kt = (o >> 9) & 7, dt = o >> 12;
        float uv = U[(dt * 16 + l16) * 256 + kt * 32 + lg * 8 + j];
        short h = f2b(uv);
        Uhi[o] = h;
        Ulo[o] = f2b(__fsub_rn(uv, b2f(h)));
    }
}

// Permute x_in and force into C-fragment order:
// idx = (((b*8 + w)*16 + c2)*64 + l)*4 + rr  (c2 = mt*8+nt, l = lg*16+l16)
// src = (b*32 + mt*16 + lg*4 + rr)*1024 + w*128 + nt*16 + l16
__global__ void perm_xf(const float* __restrict__ x_in, const float* __restrict__ f_in,
                        float* __restrict__ xperm, float* __restrict__ fperm) {
    int idx = blockIdx.x * 256 + threadIdx.x;        // 0..8388607
    int rr = idx & 3, l = (idx >> 2) & 63, c2 = (idx >> 8) & 15;
    int w = (idx >> 12) & 7, b = idx >> 15;
    int mt = c2 >> 3, nt = c2 & 7, lg = l >> 4, l16 = l & 15;
    int src = (b * 32 + mt * 16 + lg * 4 + rr) * 1024 + w * 128 + nt * 16 + l16;
    xperm[idx] = x_in[src];
    fperm[idx] = f_in[src];
}

static __device__ __forceinline__ f32x4 triple(bf16x8 ah, bf16x8 al,
                                               bf16x8 bh, bf16x8 bl, f32x4 acc) {
    acc = __builtin_amdgcn_mfma_f32_16x16x32_bf16(al, bh, acc, 0, 0, 0);
    acc = __builtin_amdgcn_mfma_f32_16x16x32_bf16(ah, bl, acc, 0, 0, 0);
    acc = __builtin_amdgcn_mfma_f32_16x16x32_bf16(ah, bh, acc, 0, 0, 0);
    return acc;
}

static __device__ __forceinline__ float wrapf(float s) {
    float a = __fadd_rn(s, PI_F);
    float m = fmodf(a, TWOPI_F);
    if (m < 0.0f) m = __fadd_rn(m, TWOPI_F);
    return __fsub_rn(m, PI_F);
}

__global__ __attribute__((amdgpu_flat_work_group_size(512, 512),
                          amdgpu_waves_per_eu(2, 2)))
void heun_fused(
    const float* __restrict__ v_in,
    const short* __restrict__ Whi, const short* __restrict__ Wlo,
    const short* __restrict__ Uhi, const short* __restrict__ Ulo,
    float* __restrict__ xhalf,    // d_out x-half: xperm during run; original-layout x at end
    float* __restrict__ vhalf)    // d_out v-half: fperm during run; original-layout v at end
{
    extern __shared__ char smem[];
    const int tid = threadIdx.x;
    const int w = tid >> 6, l = tid & 63, l16 = l & 15, lg = l >> 4;
    const int row0 = blockIdx.x << 5;
    // fragment-ordered region for this block/wave (float index); element = fbase + c2*256
    const int fbase = (blockIdx.x << 15) + (w << 12) + (l << 2);

    float vr[2][8][4];

    const int asw = (l16 & 7) << 4;
    const char* const vh0 = smem + VHI + (l16 << 11);
    const char* const vh1 = smem + VHI + ((16 + l16) << 11);
    const char* const vl0 = smem + VLO + (l16 << 11);
    const char* const vl1 = smem + VLO + ((16 + l16) << 11);
    const char* const ph0p = smem + PHI + (l16 << 9);
    const char* const ph1p = smem + PHI + ((16 + l16) << 9);
    const char* const pl0p = smem + PLO + (l16 << 9);
    const char* const pl1p = smem + PLO + ((16 + l16) << 9);

    const char* const whc = (const char*)Whi;
    const char* const wlc = (const char*)Wlo;
    const char* const uhc = (const char*)Uhi;
    const char* const ulc = (const char*)Ulo;

    int wb[2];
#pragma unroll
    for (int t = 0; t < 2; ++t) wb[t] = ((w*2 + t) << 15) + (l << 4);

    // ---- initial: load v (original layout, one-time), stage split(v) into Vb ----
#pragma unroll
    for (int mt = 0; mt < 2; ++mt)
#pragma unroll
      for (int nt = 0; nt < 8; ++nt) {
        const size_t base = (size_t)(row0 + mt*16 + lg*4) * 1024 + (w*128 + nt*16 + l16);
        const int colb0 = (w*128 + nt*16 + l16) << 1;
#pragma unroll
        for (int rr = 0; rr < 4; ++rr) {
            float val = v_in[base + (size_t)rr * 1024];
            vr[mt][nt][rr] = val;
            const int row = mt*16 + lg*4 + rr;
            const int cb = colb0 ^ ((row & 7) << 4);
            short h = f2b(val);
            *(short*)(smem + VHI + (row << 11) + cb) = h;
            *(short*)(smem + VLO + (row << 11) + cb) = f2b(__fsub_rn(val, b2f(h)));
        }
      }
    __syncthreads();

#pragma unroll 1
    for (int s = 0; s < 16; ++s) {
#pragma unroll 1
        for (int cc = 0; cc < 2; ++cc) {
            // ================= GEMM1: p[32,256] = V * W^T, wave cols w*32..+31 =====
            f32x4 p[2][2];
#pragma unroll
            for (int mt = 0; mt < 2; ++mt)
#pragma unroll
              for (int t = 0; t < 2; ++t) p[mt][t] = (f32x4){0.f, 0.f, 0.f, 0.f};

            bf16x8 qh[4][2], ql[4][2];                 // depth-4 prefetch queue
#pragma unroll
            for (int i = 0; i < 4; ++i)
#pragma unroll
              for (int t = 0; t < 2; ++t) {
                qh[i][t] = *(const bf16x8*)(whc + wb[t] + (i << 10));
                ql[i][t] = *(const bf16x8*)(wlc + wb[t] + (i << 10));
              }

#pragma unroll 1
            for (int ko = 0; ko < 8; ++ko) {
#pragma unroll
                for (int ki = 0; ki < 4; ++ki) {       // slot = ki (static)
                    const int kt = ko*4 + ki;
                    const int ao = ((kt << 6) + (lg << 4)) ^ asw;
                    bf16x8 ah0 = *(const bf16x8*)(vh0 + ao);
                    bf16x8 al0 = *(const bf16x8*)(vl0 + ao);
                    bf16x8 ah1 = *(const bf16x8*)(vh1 + ao);
                    bf16x8 al1 = *(const bf16x8*)(vl1 + ao);
#pragma unroll
                    for (int t = 0; t < 2; ++t) {
                        p[0][t] = triple(ah0, al0, qh[ki][t], ql[ki][t], p[0][t]);
                        p[1][t] = triple(ah1, al1, qh[ki][t], ql[ki][t], p[1][t]);
                    }
                    if (ko < 7) {
#pragma unroll
                        for (int t = 0; t < 2; ++t) {
                            qh[ki][t] = *(const bf16x8*)(whc + wb[t] + ((kt + 4) << 10));
                            ql[ki][t] = *(const bf16x8*)(wlc + wb[t] + ((kt + 4) << 10));
                        }
                    }
                }
            }
            // ---- square -> Pb hi/lo ----
#pragma unroll
            for (int mt = 0; mt < 2; ++mt)
#pragma unroll
              for (int t = 0; t < 2; ++t) {
                const int colb0 = (w*32 + t*16 + l16) << 1;
#pragma unroll
                for (int rr = 0; rr < 4; ++rr) {
                    const int row = mt*16 + lg*4 + rr;
                    const int cb = colb0 ^ ((row & 7) << 4);
                    float ps = __fmul_rn(p[mt][t][rr], p[mt][t][rr]);
                    short h = f2b(ps);
                    *(short*)(smem + PHI + (row << 9) + cb) = h;
                    *(short*)(smem + PLO + (row << 9) + cb) = f2b(__fsub_rn(ps, b2f(h)));
                }
              }
            __syncthreads();   // Pb complete; all Vb reads done

            // ================= GEMM2: g[32,1024] = Pb * U^T, 4 quarters ===========
#pragma unroll
            for (int q = 0; q < 4; ++q) {
                // coalesced dwordx4 prefetch of force (+x on cc==0), fragment order
                f32x4 fpre[2][2], xpre[2][2];
#pragma unroll
                for (int mt = 0; mt < 2; ++mt)
#pragma unroll
                  for (int n = 0; n < 2; ++n) {
                    const int c2 = mt*8 + q*2 + n;
                    fpre[mt][n] = *(const f32x4*)(vhalf + fbase + (c2 << 8));
                    if (cc == 0)
                        xpre[mt][n] = *(const f32x4*)(xhalf + fbase + (c2 << 8));
                  }

                bf16x8 uqh[2][2], uql[2][2];           // depth-2 prefetch queue
#pragma unroll
                for (int i = 0; i < 2; ++i)
#pragma unroll
                  for (int n = 0; n < 2; ++n) {
                    const int ub = ((w*8 + q*2 + n) << 13) + (l << 4);
                    uqh[i][n] = *(const bf16x8*)(uhc + ub + (i << 10));
                    uql[i][n] = *(const bf16x8*)(ulc + ub + (i << 10));
                  }

                f32x4 g[2][2];
#pragma unroll
                for (int mt = 0; mt < 2; ++mt)
#pragma unroll
                  for (int n = 0; n < 2; ++n) g[mt][n] = (f32x4){0.f, 0.f, 0.f, 0.f};

#pragma unroll 1
                for (int ko = 0; ko < 4; ++ko) {
#pragma unroll
                    for (int ki = 0; ki < 2; ++ki) {   // slot = ki (static)
                        const int kt = ko*2 + ki;
                        const int ao = ((kt << 6) + (lg << 4)) ^ asw;
                        bf16x8 a0h = *(const bf16x8*)(ph0p + ao);
                        bf16x8 a0l = *(const bf16x8*)(pl0p + ao);
                        bf16x8 a1h = *(const bf16x8*)(ph1p + ao);
                        bf16x8 a1l = *(const bf16x8*)(pl1p + ao);
#pragma unroll
                        for (int n = 0; n < 2; ++n) {
                            g[0][n] = triple(a0h, a0l, uqh[ki][n], uql[ki][n], g[0][n]);
                            g[1][n] = triple(a1h, a1l, uqh[ki][n], uql[ki][n], g[1][n]);
                        }
                        if (ko < 3) {
#pragma unroll
                            for (int n = 0; n < 2; ++n) {
                                const int ub = ((w*8 + q*2 + n) << 13) + (l << 4);
                                uqh[ki][n] = *(const bf16x8*)(uhc + ub + ((kt + 2) << 10));
                                uql[ki][n] = *(const bf16x8*)(ulc + ub + ((kt + 2) << 10));
                            }
                        }
                    }
                }
                // ---- epilogue (identical op order to R2/R3) ----
#pragma unroll
                for (int mt = 0; mt < 2; ++mt)
#pragma unroll
                  for (int n = 0; n < 2; ++n) {
                    const int nt = q*2 + n;
                    const int c2 = mt*8 + nt;
                    const int colb0 = (w*128 + nt*16 + l16) << 1;
                    f32x4 xnew;
#pragma unroll
                    for (int rr = 0; rr < 4; ++rr) {
                        const int row = mt*16 + lg*4 + rr;
                        const int cb = colb0 ^ ((row & 7) << 4);
                        const float dv = __fsub_rn(fpre[mt][n][rr], g[mt][n][rr]);
                        float stagev;
                        if (cc == 0) {
                            const float cv = vr[mt][nt][rr];
                            const float vp = __fadd_rn(cv, __fmul_rn(0.01f, dv));
                            const float t  = __fadd_rn(cv, vp);
                            const float sx = __fadd_rn(xpre[mt][n][rr], __fmul_rn(0.005f, t));
                            xnew[rr] = wrapf(sx);
                            vr[mt][nt][rr] = __fadd_rn(cv, __fmul_rn(0.005f, dv));
                            stagev = vp;
                        } else {
                            const float nv = __fadd_rn(vr[mt][nt][rr], __fmul_rn(0.005f, dv));
                            vr[mt][nt][rr] = nv;
                            stagev = nv;
                        }
                        short h = f2b(stagev);
                        *(short*)(smem + VHI + (row << 11) + cb) = h;
                        *(short*)(smem + VLO + (row << 11) + cb) = f2b(__fsub_rn(stagev, b2f(h)));
                    }
                    if (cc == 0)
                        *(f32x4*)(xhalf + fbase + (c2 << 8)) = xnew;
                  }
            }
            __syncthreads();   // Vb(next eval input) complete
        }
    }

    // ---- tail: read back own xperm slots (coalesced), then scatter x/v original layout
    f32x4 xv[16];
    __syncthreads();           // all epilogue xperm writes + fperm reads done
#pragma unroll
    for (int c2 = 0; c2 < 16; ++c2)
        xv[c2] = *(const f32x4*)(xhalf + fbase + (c2 << 8));
    __syncthreads();           // all reads done before overwriting halves

#pragma unroll
    for (int mt = 0; mt < 2; ++mt)
#pragma unroll
      for (int nt = 0; nt < 8; ++nt) {
        const size_t base = (size_t)(row0 + mt*16 + lg*4) * 1024 + (w*128 + nt*16 + l16);
#pragma unroll
        for (int rr = 0; rr < 4; ++rr) {
            xhalf[base + (size_t)rr * 1024] = xv[mt*8 + nt][rr];
            vhalf[base + (size_t)rr * 1024] = vr[mt][nt][rr];
        }
      }
}

extern "C" void kernel_launch(void* const* d_in, const int* in_sizes, int n_in,
                              void* d_out, int out_size, void* d_ws, size_t ws_size,
                              hipStream_t stream) {
    const float* x = (const float*)d_in[0];
    const float* v = (const float*)d_in[1];
    const float* f = (const float*)d_in[2];
    const float* U = (const float*)d_in[3];
    const float* W = (const float*)d_in[4];
    short* Whi = (short*)d_ws;           // 4 x 262144 bf16 = 2 MB
    short* Wlo = Whi + 262144;
    short* Uhi = Wlo + 262144;
    short* Ulo = Uhi + 262144;

    float* xhalf = (float*)d_out;            // xperm during run -> final x
    float* vhalf = (float*)d_out + 8388608;  // fperm during run -> final v

    hipFuncSetAttribute((const void*)heun_fused,
                        hipFuncAttributeMaxDynamicSharedMemorySize, LDS_BYTES);

    cvt_wu<<<1024, 256, 0, stream>>>(U, W, Whi, Wlo, Uhi, Ulo);
    perm_xf<<<32768, 256, 0, stream>>>(x, f, xhalf, vhalf);
    heun_fused<<<256, 512, LDS_BYTES, stream>>>(v, Whi, Wlo, Uhi, Ulo, xhalf, vhalf);
}